// Round 16
// baseline (491.279 us; speedup 1.0000x reference)
//
#include <hip/hip_runtime.h>
#include <hip/hip_bf16.h>

#define BATCH 16
#define SEQ   577
#define CDIM  768
#define HEADS 12
#define DHEAD 64
#define FFDIM 3072
#define MROWS (BATCH*SEQ)   // 9232

typedef __bf16 bf16x8 __attribute__((ext_vector_type(8)));
typedef float  f32x4  __attribute__((ext_vector_type(4)));
typedef unsigned short u16x8 __attribute__((ext_vector_type(8)));

__device__ __forceinline__ unsigned short f2bf(float f) {
    unsigned u = __builtin_bit_cast(unsigned, f);
    unsigned r = (u + 0x7FFFu + ((u >> 16) & 1u)) >> 16;
    return (unsigned short)r;
}
__device__ __forceinline__ float bf2f(unsigned short s) {
    return __builtin_bit_cast(float, (unsigned)s << 16);
}
__device__ __forceinline__ float gelu_f(float v) {
    return 0.5f * v * (1.f + erff(v * 0.7071067811865475f));
}
__device__ __forceinline__ void gll16(const void* g, void* l) {
    __builtin_amdgcn_global_load_lds(
        (const __attribute__((address_space(1))) unsigned int*)g,
        (__attribute__((address_space(3))) unsigned int*)l, 16, 0, 0);
}
#define MFMA16(a, b, c) __builtin_amdgcn_mfma_f32_16x16x32_bf16((a), (b), (c), 0, 0, 0)

// ---------------- weight conversion: fp32 -> bf16, transposed to [out][in] ----
#define S0 (2304*768)
#define S1 (768*768)
#define S2 (768*3072)
#define S3 (3072*768)
#define STOT (S0+S1+S2+S3)

__global__ __launch_bounds__(256) void convert_w(
    const float* __restrict__ wq, const float* __restrict__ wk, const float* __restrict__ wv,
    const float* __restrict__ wo, const float* __restrict__ w1, const float* __restrict__ w2,
    const float* __restrict__ bq, const float* __restrict__ bk, const float* __restrict__ bv,
    unsigned short* __restrict__ wqkvT, unsigned short* __restrict__ woT,
    unsigned short* __restrict__ w1T, unsigned short* __restrict__ w2T,
    float* __restrict__ bqkv)
{
    for (size_t id = (size_t)blockIdx.x * 256 + threadIdx.x; id < STOT + 2304; id += (size_t)gridDim.x * 256) {
        if (id < S0) {
            int n = (int)(id / 768), k = (int)(id % 768);
            const float* w = (n < 768) ? wq : (n < 1536) ? wk : wv;
            int c = (n < 768) ? n : (n < 1536) ? n - 768 : n - 1536;
            wqkvT[id] = f2bf(w[(size_t)k * 768 + c]);
        } else if (id < S0 + S1) {
            size_t i2 = id - S0; int n = (int)(i2 / 768), k = (int)(i2 % 768);
            woT[i2] = f2bf(wo[(size_t)k * 768 + n]);
        } else if (id < S0 + S1 + S2) {
            size_t i3 = id - S0 - S1; int n = (int)(i3 / 768), k = (int)(i3 % 768);
            w1T[i3] = f2bf(w1[(size_t)k * 3072 + n]);
        } else if (id < STOT) {
            size_t i4 = id - S0 - S1 - S2; int n = (int)(i4 / 3072), k = (int)(i4 % 3072);
            w2T[i4] = f2bf(w2[(size_t)k * 768 + n]);
        } else {
            int c = (int)(id - STOT);
            float v = (c < 768) ? bq[c] : (c < 1536) ? bk[c - 768] : bv[c - 1536];
            bqkv[c] = v;
        }
    }
}

// ---------------- LayerNorm (row of 768) -> bf16 ------------------------------
__global__ __launch_bounds__(256) void ln_bf16(
    const float* __restrict__ x, const float* __restrict__ g, const float* __restrict__ b,
    unsigned short* __restrict__ out)
{
    int row = blockIdx.x;
    int t = threadIdx.x;
    const float* xr = x + (size_t)row * CDIM;
    float v0 = xr[t], v1 = xr[t + 256], v2 = xr[t + 512];
    float s = v0 + v1 + v2;
    float q = v0 * v0 + v1 * v1 + v2 * v2;
    __shared__ float red[8];
    for (int o = 32; o > 0; o >>= 1) { s += __shfl_down(s, o); q += __shfl_down(q, o); }
    int wid = t >> 6;
    if ((t & 63) == 0) { red[wid] = s; red[4 + wid] = q; }
    __syncthreads();
    if (t == 0) {
        float S = red[0] + red[1] + red[2] + red[3];
        float Q = red[4] + red[5] + red[6] + red[7];
        float mu = S * (1.f / CDIM);
        float var = Q * (1.f / CDIM) - mu * mu;
        red[0] = mu; red[1] = rsqrtf(var + 1e-5f);
    }
    __syncthreads();
    float mu = red[0], rs = red[1];
    unsigned short* orow = out + (size_t)row * CDIM;
    orow[t]       = f2bf((v0 - mu) * rs * g[t]       + b[t]);
    orow[t + 256] = f2bf((v1 - mu) * rs * g[t + 256] + b[t + 256]);
    orow[t + 512] = f2bf((v2 - mu) * rs * g[t + 512] + b[t + 512]);
}

// ---------------- GEMM 128x128, BK=64, 8 waves: A via LDS, B direct-global ----
// C[M,N] = A[M,K](bf16) @ Bt[N,K]^T(bf16) + bias.
// EPI 0: store bf16.  EPI 1: float out = resid + v.  EPI 2: store bf16(gelu(v)).
// B panels are small (<=4.7 MB) and XCD-L2-resident (swizzle) -> B fragments
// read DIRECT from global (dwordx4/lane) with 1-step register prefetch
// (attn's vA/vB idiom). A stays on the round-14 gll16+XOR-swizzle path.
// Staging halves (2 gll16), ds_read 12->8, LDS 32 KB -> 3 blocks/CU.
template<int EPI>
__global__ __launch_bounds__(512, 4) void gemm128(
    const unsigned short* __restrict__ A, const unsigned short* __restrict__ Bt,
    const float* __restrict__ bias, void* __restrict__ Cout,
    const float* __restrict__ resid, int M, int Nn, int K)
{
    __shared__ __align__(16) unsigned short As[2][128 * 64];

    int t = threadIdx.x;
    // bijective XCD swizzle (m204)
    int gx = gridDim.x;
    int nwg = gx * gridDim.y;
    int bid = blockIdx.y * gx + blockIdx.x;
    int qc = nwg >> 3, rc = nwg & 7;
    int xcd = bid & 7, loc = bid >> 3;
    int swz = (xcd < rc ? xcd * (qc + 1) : rc * (qc + 1) + (xcd - rc) * qc) + loc;
    int nbase = (swz % gx) * 128;
    int mbase = (swz / gx) * 128;

    int lane = t & 63, w = t >> 6;          // w = 0..7
    int wm = w >> 2, wn = w & 3;            // 2(M) x 4(N) wave grid
    int lr = lane & 15, lk = lane >> 4;

    // A staging: wave w covers rows w*16..w*16+15 (two 8-row gll16 sweeps)
    int srow = lane >> 3;                      // 0..7
    int scol = ((lane & 7) * 8) ^ (srow << 3); // pre-swizzled col (elems)

    int arow0 = min(mbase + w * 16 + srow,     M - 1);
    int arow1 = min(mbase + w * 16 + 8 + srow, M - 1);
    const unsigned short* ap0 = A + (size_t)arow0 * K + scol;
    const unsigned short* ap1 = A + (size_t)arow1 * K + scol;
    char* lA[2] = { (char*)&As[0][0] + w * 2048, (char*)&As[1][0] + w * 2048 };

    // B direct-global fragment pointers: row = nbase + wn*32 + ni*16 + lr
    const unsigned short* bp[2];
#pragma unroll
    for (int ni = 0; ni < 2; ni++)
        bp[ni] = Bt + (size_t)(nbase + wn * 32 + ni * 16 + lr) * K + lk * 8;

    f32x4 acc[4][2] = {};

    // prologue: stage A(0); prefetch B(0)
    gll16(ap0, lA[0]);
    gll16(ap1, lA[0] + 1024);
    bf16x8 bcur[2][2], bnxt[2][2];
#pragma unroll
    for (int ni = 0; ni < 2; ni++)
#pragma unroll
        for (int ks = 0; ks < 2; ks++)
            bcur[ni][ks] = *(const bf16x8*)(bp[ni] + ks * 32);

    for (int kt = 0; kt < K; kt += 64) {
        int buf = (kt >> 6) & 1;
        __syncthreads();               // A(kt) staged (vmcnt(0) drain)
        if (kt + 64 < K) {             // issue A(kt+64) + prefetch B(kt+64)
            gll16(ap0 + kt + 64, lA[buf ^ 1]);
            gll16(ap1 + kt + 64, lA[buf ^ 1] + 1024);
#pragma unroll
            for (int ni = 0; ni < 2; ni++)
#pragma unroll
                for (int ks = 0; ks < 2; ks++)
                    bnxt[ni][ks] = *(const bf16x8*)(bp[ni] + kt + 64 + ks * 32);
        }
        bf16x8 af[4][2];
#pragma unroll
        for (int mi = 0; mi < 4; mi++) {
            int row = wm * 64 + mi * 16 + lr;
#pragma unroll
            for (int ks = 0; ks < 2; ks++)
                af[mi][ks] = *(const bf16x8*)((char*)&As[buf][0] + row * 128 +
                                (((ks * 64 + lk * 16)) ^ ((lr & 7) << 4)));
        }
#pragma unroll
        for (int ks = 0; ks < 2; ks++)
#pragma unroll
            for (int mi = 0; mi < 4; mi++)
#pragma unroll
                for (int ni = 0; ni < 2; ni++)
                    acc[mi][ni] = MFMA16(af[mi][ks], bcur[ni][ks], acc[mi][ni]);
        // rotate B prefetch (static indices, SSA copies)
#pragma unroll
        for (int ni = 0; ni < 2; ni++)
#pragma unroll
            for (int ks = 0; ks < 2; ks++)
                bcur[ni][ks] = bnxt[ni][ks];
    }

#pragma unroll
    for (int mi = 0; mi < 4; mi++) {
#pragma unroll
        for (int ni = 0; ni < 2; ni++) {
            int col = nbase + wn * 32 + ni * 16 + lr;
            float bcol = bias[col];
#pragma unroll
            for (int i = 0; i < 4; i++) {
                int row = mbase + wm * 64 + mi * 16 + lk * 4 + i;
                if (row >= M) continue;
                float v = acc[mi][ni][i] + bcol;
                if (EPI == 0) {
                    ((unsigned short*)Cout)[(size_t)row * Nn + col] = f2bf(v);
                } else if (EPI == 1) {
                    ((float*)Cout)[(size_t)row * Nn + col] = resid[(size_t)row * Nn + col] + v;
                } else {
                    ((unsigned short*)Cout)[(size_t)row * Nn + col] = f2bf(gelu_f(v));
                }
            }
        }
    }
}

// ---------------- fused attention v6: XCD swizzle + fused exp (no max-pass) ---
__global__ __launch_bounds__(256) void attn_kernel(
    const unsigned short* __restrict__ qkv, unsigned short* __restrict__ attno)
{
    int bid = blockIdx.y * 19 + blockIdx.x;
    int swzb = (bid & 7) * 456 + (bid >> 3);   // nwg=3648, rc=0
    int qt = swzb % 19;
    int bh = swzb / 19;
    int b = bh / HEADS, h = bh % HEADS;
    int t = threadIdx.x;
    int lane = t & 63, w = t >> 6;
    int lr = lane & 15, lk = lane >> 4, k0 = lk * 8;

    const size_t baseRow = (size_t)b * SEQ;
    const unsigned short* Qp = qkv + baseRow * 2304 + h * 64;
    const unsigned short* Kp = Qp + 768;
    const unsigned short* Vp = Qp + 1536;

    __shared__ __align__(16) unsigned short sSP[32][648];  // P (bf16), 81 slots/row
    __shared__ __align__(16) unsigned short sVt[64 * 64];  // V^T chunk, XOR-swizzled
    __shared__ float sRedS[4][32];

    // ---- Q fragments in registers; V chunk-0 load issued early (T14) ----------
    bf16x8 afr[2][2];
#pragma unroll
    for (int mi = 0; mi < 2; mi++) {
        int qr = qt * 32 + mi * 16 + lr; if (qr > SEQ - 1) qr = SEQ - 1;
#pragma unroll
        for (int ks = 0; ks < 2; ks++)
            afr[mi][ks] = *(const bf16x8*)(Qp + (size_t)qr * 2304 + ks * 32 + k0);
    }
    int jp = t >> 3;               // 0..31 -> j pair within chunk
    int dg = (t & 7) * 8;          // d group
    u16x8 vA, vB;
    vA = *(const u16x8*)(Vp + (size_t)min(jp * 2,     SEQ - 1) * 2304 + dg);
    vB = *(const u16x8*)(Vp + (size_t)min(jp * 2 + 1, SEQ - 1) * 2304 + dg);

    // ---- QK^T fused with exp + P-write + row-sum: wave w owns j-tiles w+4it ---
    float sm[2][4] = {};
#pragma unroll
    for (int it = 0; it < 10; it++) {
        int jt = w + it * 4;
        int col = jt * 16 + lr;
        int j = min(col, SEQ - 1);
        f32x4 a0 = {}, a1 = {};
#pragma unroll
        for (int ks = 0; ks < 2; ks++) {
            bf16x8 bfr = *(const bf16x8*)(Kp + (size_t)j * 2304 + ks * 32 + k0);
            a0 = MFMA16(afr[0][ks], bfr, a0);
            a1 = MFMA16(afr[1][ks], bfr, a1);
        }
        bool valid = col < SEQ;
#pragma unroll
        for (int i = 0; i < 4; i++) {
            float p0 = valid ? __expf(0.125f * a0[i]) : 0.f;
            float p1 = valid ? __expf(0.125f * a1[i]) : 0.f;
            sm[0][i] += p0;
            sm[1][i] += p1;
            sSP[lk * 4 + i][col]      = f2bf(p0);
            sSP[16 + lk * 4 + i][col] = f2bf(p1);
        }
    }
    // reduce row-sums over the 16 lr lanes, publish per-wave
#pragma unroll
    for (int mi = 0; mi < 2; mi++) {
#pragma unroll
        for (int i = 0; i < 4; i++) {
            float v = sm[mi][i];
            v += __shfl_xor(v, 1);
            v += __shfl_xor(v, 2);
            v += __shfl_xor(v, 4);
            v += __shfl_xor(v, 8);
            sm[mi][i] = v;
        }
    }
    if (lr == 0)
#pragma unroll
        for (int mi = 0; mi < 2; mi++)
#pragma unroll
            for (int i = 0; i < 4; i++)
                sRedS[w][mi * 16 + lk * 4 + i] = sm[mi][i];
    __syncthreads();

    // ---- PV: 10 chunks of 64 j; T14 pipeline: write regs->LDS, issue next -----
    f32x4 oacc[2] = {};
    int d = w * 16 + lr;
    int fx = ((d & 7) ^ (d >> 3)) << 4;
    for (int jc = 0; jc < 10; jc++) {
        __syncthreads();               // previous chunk's sVt readers done
#pragma unroll
        for (int e = 0; e < 8; e++) {
            unsigned val = (unsigned)vA[e] | ((unsigned)vB[e] << 16);
            int r = dg + e;
            int off = (r * 128 + jp * 4) ^ ((((r & 7) ^ (r >> 3)) & 7) << 4);
            *(unsigned*)((char*)sVt + off) = val;
        }
        if (jc < 9) {
            int j0 = (jc + 1) * 64 + jp * 2;
            vA = *(const u16x8*)(Vp + (size_t)min(j0,     SEQ - 1) * 2304 + dg);
            vB = *(const u16x8*)(Vp + (size_t)min(j0 + 1, SEQ - 1) * 2304 + dg);
        }
        __syncthreads();               // sVt(jc) ready
#pragma unroll
        for (int ks = 0; ks < 2; ks++) {
            bf16x8 vb = *(const bf16x8*)((char*)sVt + ((d * 128 + ks * 64 + lk * 16) ^ fx));
#pragma unroll
            for (int mi = 0; mi < 2; mi++) {
                bf16x8 pa = *(const bf16x8*)&sSP[mi * 16 + lr][jc * 64 + ks * 32 + k0];
                oacc[mi] = MFMA16(pa, vb, oacc[mi]);
            }
        }
    }

#pragma unroll
    for (int mi = 0; mi < 2; mi++) {
#pragma unroll
        for (int i = 0; i < 4; i++) {
            int ri = mi * 16 + lk * 4 + i;
            int qr = qt * 32 + ri;
            if (qr < SEQ) {
                float rs = sRedS[0][ri] + sRedS[1][ri] + sRedS[2][ri] + sRedS[3][ri];
                float ov = oacc[mi][i] / rs;
                attno[(baseRow + qr) * CDIM + h * 64 + w * 16 + lr] = f2bf(ov);
            }
        }
    }
}

// ---------------- host launch --------------------------------------------------
extern "C" void kernel_launch(void* const* d_in, const int* in_sizes, int n_in,
                              void* d_out, int out_size, void* d_ws, size_t ws_size,
                              hipStream_t stream) {
    const float* x     = (const float*)d_in[0];
    const float* ln1_g = (const float*)d_in[2];
    const float* ln1_b = (const float*)d_in[3];
    const float* wq    = (const float*)d_in[4];
    const float* bq    = (const float*)d_in[5];
    const float* wk    = (const float*)d_in[6];
    const float* bk    = (const float*)d_in[7];
    const float* wv    = (const float*)d_in[8];
    const float* bv    = (const float*)d_in[9];
    const float* wo    = (const float*)d_in[10];
    const float* bo    = (const float*)d_in[11];
    const float* ln2_g = (const float*)d_in[12];
    const float* ln2_b = (const float*)d_in[13];
    const float* w1    = (const float*)d_in[14];
    const float* b1    = (const float*)d_in[15];
    const float* w2    = (const float*)d_in[16];
    const float* b2    = (const float*)d_in[17];
    float* out = (float*)d_out;

    char* ws = (char*)d_ws;
    unsigned short* wqkvT = (unsigned short*)(ws + 0);
    unsigned short* woT   = (unsigned short*)(ws + 3538944);
    unsigned short* w1T   = (unsigned short*)(ws + 4718592);
    unsigned short* w2T   = (unsigned short*)(ws + 9437184);
    float*          bqkv  = (float*)         (ws + 14155776);
    unsigned short* qkv   = (unsigned short*)(ws + 14164992);  // 9232 x 2304
    unsigned short* hbuf  = (unsigned short*)(ws + 56706048);  // 9232 x 768
    unsigned short* attno = (unsigned short*)(ws + 70886400);  // 9232 x 768 (reused for h2)
    unsigned short* mid   = (unsigned short*)(ws + 14164992);  // 9232 x 3072 aliases qkv+h (both dead)
    unsigned short* h2    = attno;                              // attno dead after o-proj

    // 1. weights -> bf16 transposed
    convert_w<<<4096, 256, 0, stream>>>(wq, wk, wv, wo, w1, w2, bq, bk, bv,
                                        wqkvT, woT, w1T, w2T, bqkv);
    // 2. LN1
    ln_bf16<<<MROWS, 256, 0, stream>>>(x, ln1_g, ln1_b, hbuf);
    // 3. QKV projection: qkv = h @ Wqkv + bqkv
    gemm128<0><<<dim3(2304 / 128, (MROWS + 127) / 128), 512, 0, stream>>>(
        hbuf, wqkvT, bqkv, qkv, nullptr, MROWS, 2304, 768);
    // 4. attention
    attn_kernel<<<dim3(19, BATCH * HEADS), 256, 0, stream>>>(qkv, attno);
    // 5. o-proj + residual: out = x + attno @ wo + bo
    gemm128<1><<<dim3(768 / 128, (MROWS + 127) / 128), 512, 0, stream>>>(
        attno, woT, bo, out, x, MROWS, 768, 768);
    // 6. LN2 (reads d_out) -> h2
    ln_bf16<<<MROWS, 256, 0, stream>>>(out, ln2_g, ln2_b, h2);
    // 7. MLP1 + gelu: mid = gelu(h2 @ w1 + b1)
    gemm128<2><<<dim3(3072 / 128, (MROWS + 127) / 128), 512, 0, stream>>>(
        h2, w1T, b1, mid, nullptr, MROWS, 3072, 768);
    // 8. MLP2 + residual in-place: out += mid @ w2 + b2
    gemm128<1><<<dim3(768 / 128, (MROWS + 127) / 128), 512, 0, stream>>>(
        mid, w2T, b2, out, out, MROWS, 768, 3072);
}

// Round 17
// 348.271 us; speedup vs baseline: 1.4106x; 1.4106x over previous
//
#include <hip/hip_runtime.h>
#include <hip/hip_bf16.h>

#define BATCH 16
#define SEQ   577
#define CDIM  768
#define HEADS 12
#define DHEAD 64
#define FFDIM 3072
#define MROWS (BATCH*SEQ)   // 9232

typedef __bf16 bf16x8 __attribute__((ext_vector_type(8)));
typedef float  f32x4  __attribute__((ext_vector_type(4)));
typedef unsigned short u16x8 __attribute__((ext_vector_type(8)));

__device__ __forceinline__ unsigned short f2bf(float f) {
    unsigned u = __builtin_bit_cast(unsigned, f);
    unsigned r = (u + 0x7FFFu + ((u >> 16) & 1u)) >> 16;
    return (unsigned short)r;
}
__device__ __forceinline__ float bf2f(unsigned short s) {
    return __builtin_bit_cast(float, (unsigned)s << 16);
}
__device__ __forceinline__ float gelu_f(float v) {
    return 0.5f * v * (1.f + erff(v * 0.7071067811865475f));
}
__device__ __forceinline__ void gll16(const void* g, void* l) {
    __builtin_amdgcn_global_load_lds(
        (const __attribute__((address_space(1))) unsigned int*)g,
        (__attribute__((address_space(3))) unsigned int*)l, 16, 0, 0);
}
#define MFMA16(a, b, c) __builtin_amdgcn_mfma_f32_16x16x32_bf16((a), (b), (c), 0, 0, 0)

// ---------------- weight conversion: fp32 -> bf16, transposed to [out][in] ----
#define S0 (2304*768)
#define S1 (768*768)
#define S2 (768*3072)
#define S3 (3072*768)
#define STOT (S0+S1+S2+S3)

__global__ __launch_bounds__(256) void convert_w(
    const float* __restrict__ wq, const float* __restrict__ wk, const float* __restrict__ wv,
    const float* __restrict__ wo, const float* __restrict__ w1, const float* __restrict__ w2,
    const float* __restrict__ bq, const float* __restrict__ bk, const float* __restrict__ bv,
    unsigned short* __restrict__ wqkvT, unsigned short* __restrict__ woT,
    unsigned short* __restrict__ w1T, unsigned short* __restrict__ w2T,
    float* __restrict__ bqkv)
{
    for (size_t id = (size_t)blockIdx.x * 256 + threadIdx.x; id < STOT + 2304; id += (size_t)gridDim.x * 256) {
        if (id < S0) {
            int n = (int)(id / 768), k = (int)(id % 768);
            const float* w = (n < 768) ? wq : (n < 1536) ? wk : wv;
            int c = (n < 768) ? n : (n < 1536) ? n - 768 : n - 1536;
            wqkvT[id] = f2bf(w[(size_t)k * 768 + c]);
        } else if (id < S0 + S1) {
            size_t i2 = id - S0; int n = (int)(i2 / 768), k = (int)(i2 % 768);
            woT[i2] = f2bf(wo[(size_t)k * 768 + n]);
        } else if (id < S0 + S1 + S2) {
            size_t i3 = id - S0 - S1; int n = (int)(i3 / 768), k = (int)(i3 % 768);
            w1T[i3] = f2bf(w1[(size_t)k * 3072 + n]);
        } else if (id < STOT) {
            size_t i4 = id - S0 - S1 - S2; int n = (int)(i4 / 3072), k = (int)(i4 % 3072);
            w2T[i4] = f2bf(w2[(size_t)k * 768 + n]);
        } else {
            int c = (int)(id - STOT);
            float v = (c < 768) ? bq[c] : (c < 1536) ? bk[c - 768] : bv[c - 1536];
            bqkv[c] = v;
        }
    }
}

// ---------------- LayerNorm (row of 768) -> bf16 ------------------------------
__global__ __launch_bounds__(256) void ln_bf16(
    const float* __restrict__ x, const float* __restrict__ g, const float* __restrict__ b,
    unsigned short* __restrict__ out)
{
    int row = blockIdx.x;
    int t = threadIdx.x;
    const float* xr = x + (size_t)row * CDIM;
    float v0 = xr[t], v1 = xr[t + 256], v2 = xr[t + 512];
    float s = v0 + v1 + v2;
    float q = v0 * v0 + v1 * v1 + v2 * v2;
    __shared__ float red[8];
    for (int o = 32; o > 0; o >>= 1) { s += __shfl_down(s, o); q += __shfl_down(q, o); }
    int wid = t >> 6;
    if ((t & 63) == 0) { red[wid] = s; red[4 + wid] = q; }
    __syncthreads();
    if (t == 0) {
        float S = red[0] + red[1] + red[2] + red[3];
        float Q = red[4] + red[5] + red[6] + red[7];
        float mu = S * (1.f / CDIM);
        float var = Q * (1.f / CDIM) - mu * mu;
        red[0] = mu; red[1] = rsqrtf(var + 1e-5f);
    }
    __syncthreads();
    float mu = red[0], rs = red[1];
    unsigned short* orow = out + (size_t)row * CDIM;
    orow[t]       = f2bf((v0 - mu) * rs * g[t]       + b[t]);
    orow[t + 256] = f2bf((v1 - mu) * rs * g[t + 256] + b[t + 256]);
    orow[t + 512] = f2bf((v2 - mu) * rs * g[t + 512] + b[t + 512]);
}

// ---------------- GEMM 128x128, BK=64, dbuf, 8 waves, XOR-swizzled LDS --------
// (round-14/15 structure — best measured; round-16's B-direct regressed)
template<int EPI>
__global__ __launch_bounds__(512, 4) void gemm128(
    const unsigned short* __restrict__ A, const unsigned short* __restrict__ Bt,
    const float* __restrict__ bias, void* __restrict__ Cout,
    const float* __restrict__ resid, int M, int Nn, int K)
{
    __shared__ __align__(16) unsigned short As[2][128 * 64];
    __shared__ __align__(16) unsigned short Bs[2][128 * 64];

    int t = threadIdx.x;
    int gx = gridDim.x;
    int nwg = gx * gridDim.y;
    int bid = blockIdx.y * gx + blockIdx.x;
    int qc = nwg >> 3, rc = nwg & 7;
    int xcd = bid & 7, loc = bid >> 3;
    int swz = (xcd < rc ? xcd * (qc + 1) : rc * (qc + 1) + (xcd - rc) * qc) + loc;
    int nbase = (swz % gx) * 128;
    int mbase = (swz / gx) * 128;

    int lane = t & 63, w = t >> 6;          // w = 0..7
    int wm = w >> 2, wn = w & 3;            // 2(M) x 4(N) wave grid
    int lr = lane & 15, lk = lane >> 4;

    int srow = lane >> 3;                      // 0..7 row within 8-row sweep
    int scol = ((lane & 7) * 8) ^ (srow << 3); // pre-swizzled col (elems)

    int arow0 = min(mbase + w * 16 + srow,     M - 1);
    int arow1 = min(mbase + w * 16 + 8 + srow, M - 1);
    int brow0 = nbase + w * 16 + srow;
    int brow1 = nbase + w * 16 + 8 + srow;
    const unsigned short* ap0 = A  + (size_t)arow0 * K + scol;
    const unsigned short* ap1 = A  + (size_t)arow1 * K + scol;
    const unsigned short* bp0 = Bt + (size_t)brow0 * K + scol;
    const unsigned short* bp1 = Bt + (size_t)brow1 * K + scol;
    char* lA[2] = { (char*)&As[0][0] + w * 2048, (char*)&As[1][0] + w * 2048 };
    char* lB[2] = { (char*)&Bs[0][0] + w * 2048, (char*)&Bs[1][0] + w * 2048 };

    f32x4 acc[4][2] = {};

    gll16(ap0, lA[0]);
    gll16(ap1, lA[0] + 1024);
    gll16(bp0, lB[0]);
    gll16(bp1, lB[0] + 1024);

    for (int kt = 0; kt < K; kt += 64) {
        int buf = (kt >> 6) & 1;
        __syncthreads();
        if (kt + 64 < K) {
            gll16(ap0 + kt + 64, lA[buf ^ 1]);
            gll16(ap1 + kt + 64, lA[buf ^ 1] + 1024);
            gll16(bp0 + kt + 64, lB[buf ^ 1]);
            gll16(bp1 + kt + 64, lB[buf ^ 1] + 1024);
        }
        bf16x8 af[4][2], bfv[2][2];
#pragma unroll
        for (int mi = 0; mi < 4; mi++) {
            int row = wm * 64 + mi * 16 + lr;
#pragma unroll
            for (int ks = 0; ks < 2; ks++)
                af[mi][ks] = *(const bf16x8*)((char*)&As[buf][0] + row * 128 +
                                (((ks * 64 + lk * 16)) ^ ((lr & 7) << 4)));
        }
#pragma unroll
        for (int ni = 0; ni < 2; ni++) {
            int row = wn * 32 + ni * 16 + lr;
#pragma unroll
            for (int ks = 0; ks < 2; ks++)
                bfv[ni][ks] = *(const bf16x8*)((char*)&Bs[buf][0] + row * 128 +
                                (((ks * 64 + lk * 16)) ^ ((lr & 7) << 4)));
        }
#pragma unroll
        for (int ks = 0; ks < 2; ks++)
#pragma unroll
            for (int mi = 0; mi < 4; mi++)
#pragma unroll
                for (int ni = 0; ni < 2; ni++)
                    acc[mi][ni] = MFMA16(af[mi][ks], bfv[ni][ks], acc[mi][ni]);
    }

#pragma unroll
    for (int mi = 0; mi < 4; mi++) {
#pragma unroll
        for (int ni = 0; ni < 2; ni++) {
            int col = nbase + wn * 32 + ni * 16 + lr;
            float bcol = bias[col];
#pragma unroll
            for (int i = 0; i < 4; i++) {
                int row = mbase + wm * 64 + mi * 16 + lk * 4 + i;
                if (row >= M) continue;
                float v = acc[mi][ni][i] + bcol;
                if (EPI == 0) {
                    ((unsigned short*)Cout)[(size_t)row * Nn + col] = f2bf(v);
                } else if (EPI == 1) {
                    ((float*)Cout)[(size_t)row * Nn + col] = resid[(size_t)row * Nn + col] + v;
                } else {
                    ((unsigned short*)Cout)[(size_t)row * Nn + col] = f2bf(gelu_f(v));
                }
            }
        }
    }
}

// ---------------- fused attention v7: v6 + setprio around MFMA (T5) -----------
__global__ __launch_bounds__(256) void attn_kernel(
    const unsigned short* __restrict__ qkv, unsigned short* __restrict__ attno)
{
    int bid = blockIdx.y * 19 + blockIdx.x;
    int swzb = (bid & 7) * 456 + (bid >> 3);   // nwg=3648, rc=0
    int qt = swzb % 19;
    int bh = swzb / 19;
    int b = bh / HEADS, h = bh % HEADS;
    int t = threadIdx.x;
    int lane = t & 63, w = t >> 6;
    int lr = lane & 15, lk = lane >> 4, k0 = lk * 8;

    const size_t baseRow = (size_t)b * SEQ;
    const unsigned short* Qp = qkv + baseRow * 2304 + h * 64;
    const unsigned short* Kp = Qp + 768;
    const unsigned short* Vp = Qp + 1536;

    __shared__ __align__(16) unsigned short sSP[32][648];  // P (bf16), 81 slots/row
    __shared__ __align__(16) unsigned short sVt[64 * 64];  // V^T chunk, XOR-swizzled
    __shared__ float sRedS[4][32];

    // ---- Q fragments in registers; V chunk-0 load issued early (T14) ----------
    bf16x8 afr[2][2];
#pragma unroll
    for (int mi = 0; mi < 2; mi++) {
        int qr = qt * 32 + mi * 16 + lr; if (qr > SEQ - 1) qr = SEQ - 1;
#pragma unroll
        for (int ks = 0; ks < 2; ks++)
            afr[mi][ks] = *(const bf16x8*)(Qp + (size_t)qr * 2304 + ks * 32 + k0);
    }
    int jp = t >> 3;               // 0..31 -> j pair within chunk
    int dg = (t & 7) * 8;          // d group
    u16x8 vA, vB;
    vA = *(const u16x8*)(Vp + (size_t)min(jp * 2,     SEQ - 1) * 2304 + dg);
    vB = *(const u16x8*)(Vp + (size_t)min(jp * 2 + 1, SEQ - 1) * 2304 + dg);

    // ---- QK^T fused with exp + P-write + row-sum: wave w owns j-tiles w+4it ---
    float sm[2][4] = {};
#pragma unroll
    for (int it = 0; it < 10; it++) {
        int jt = w + it * 4;
        int col = jt * 16 + lr;
        int j = min(col, SEQ - 1);
        f32x4 a0 = {}, a1 = {};
        __builtin_amdgcn_s_setprio(1);
#pragma unroll
        for (int ks = 0; ks < 2; ks++) {
            bf16x8 bfr = *(const bf16x8*)(Kp + (size_t)j * 2304 + ks * 32 + k0);
            a0 = MFMA16(afr[0][ks], bfr, a0);
            a1 = MFMA16(afr[1][ks], bfr, a1);
        }
        __builtin_amdgcn_s_setprio(0);
        bool valid = col < SEQ;
#pragma unroll
        for (int i = 0; i < 4; i++) {
            float p0 = valid ? __expf(0.125f * a0[i]) : 0.f;
            float p1 = valid ? __expf(0.125f * a1[i]) : 0.f;
            sm[0][i] += p0;
            sm[1][i] += p1;
            sSP[lk * 4 + i][col]      = f2bf(p0);
            sSP[16 + lk * 4 + i][col] = f2bf(p1);
        }
    }
    // reduce row-sums over the 16 lr lanes, publish per-wave
#pragma unroll
    for (int mi = 0; mi < 2; mi++) {
#pragma unroll
        for (int i = 0; i < 4; i++) {
            float v = sm[mi][i];
            v += __shfl_xor(v, 1);
            v += __shfl_xor(v, 2);
            v += __shfl_xor(v, 4);
            v += __shfl_xor(v, 8);
            sm[mi][i] = v;
        }
    }
    if (lr == 0)
#pragma unroll
        for (int mi = 0; mi < 2; mi++)
#pragma unroll
            for (int i = 0; i < 4; i++)
                sRedS[w][mi * 16 + lk * 4 + i] = sm[mi][i];
    __syncthreads();

    // ---- PV: 10 chunks of 64 j; T14 pipeline: write regs->LDS, issue next -----
    f32x4 oacc[2] = {};
    int d = w * 16 + lr;
    int fx = ((d & 7) ^ (d >> 3)) << 4;
    for (int jc = 0; jc < 10; jc++) {
        __syncthreads();               // previous chunk's sVt readers done
#pragma unroll
        for (int e = 0; e < 8; e++) {
            unsigned val = (unsigned)vA[e] | ((unsigned)vB[e] << 16);
            int r = dg + e;
            int off = (r * 128 + jp * 4) ^ ((((r & 7) ^ (r >> 3)) & 7) << 4);
            *(unsigned*)((char*)sVt + off) = val;
        }
        if (jc < 9) {
            int j0 = (jc + 1) * 64 + jp * 2;
            vA = *(const u16x8*)(Vp + (size_t)min(j0,     SEQ - 1) * 2304 + dg);
            vB = *(const u16x8*)(Vp + (size_t)min(j0 + 1, SEQ - 1) * 2304 + dg);
        }
        __syncthreads();               // sVt(jc) ready
        __builtin_amdgcn_s_setprio(1);
#pragma unroll
        for (int ks = 0; ks < 2; ks++) {
            bf16x8 vb = *(const bf16x8*)((char*)sVt + ((d * 128 + ks * 64 + lk * 16) ^ fx));
#pragma unroll
            for (int mi = 0; mi < 2; mi++) {
                bf16x8 pa = *(const bf16x8*)&sSP[mi * 16 + lr][jc * 64 + ks * 32 + k0];
                oacc[mi] = MFMA16(pa, vb, oacc[mi]);
            }
        }
        __builtin_amdgcn_s_setprio(0);
    }

#pragma unroll
    for (int mi = 0; mi < 2; mi++) {
#pragma unroll
        for (int i = 0; i < 4; i++) {
            int ri = mi * 16 + lk * 4 + i;
            int qr = qt * 32 + ri;
            if (qr < SEQ) {
                float rs = sRedS[0][ri] + sRedS[1][ri] + sRedS[2][ri] + sRedS[3][ri];
                float ov = oacc[mi][i] / rs;
                attno[(baseRow + qr) * CDIM + h * 64 + w * 16 + lr] = f2bf(ov);
            }
        }
    }
}

// ---------------- host launch --------------------------------------------------
extern "C" void kernel_launch(void* const* d_in, const int* in_sizes, int n_in,
                              void* d_out, int out_size, void* d_ws, size_t ws_size,
                              hipStream_t stream) {
    const float* x     = (const float*)d_in[0];
    const float* ln1_g = (const float*)d_in[2];
    const float* ln1_b = (const float*)d_in[3];
    const float* wq    = (const float*)d_in[4];
    const float* bq    = (const float*)d_in[5];
    const float* wk    = (const float*)d_in[6];
    const float* bk    = (const float*)d_in[7];
    const float* wv    = (const float*)d_in[8];
    const float* bv    = (const float*)d_in[9];
    const float* wo    = (const float*)d_in[10];
    const float* bo    = (const float*)d_in[11];
    const float* ln2_g = (const float*)d_in[12];
    const float* ln2_b = (const float*)d_in[13];
    const float* w1    = (const float*)d_in[14];
    const float* b1    = (const float*)d_in[15];
    const float* w2    = (const float*)d_in[16];
    const float* b2    = (const float*)d_in[17];
    float* out = (float*)d_out;

    char* ws = (char*)d_ws;
    unsigned short* wqkvT = (unsigned short*)(ws + 0);
    unsigned short* woT   = (unsigned short*)(ws + 3538944);
    unsigned short* w1T   = (unsigned short*)(ws + 4718592);
    unsigned short* w2T   = (unsigned short*)(ws + 9437184);
    float*          bqkv  = (float*)         (ws + 14155776);
    unsigned short* qkv   = (unsigned short*)(ws + 14164992);  // 9232 x 2304
    unsigned short* hbuf  = (unsigned short*)(ws + 56706048);  // 9232 x 768
    unsigned short* attno = (unsigned short*)(ws + 70886400);  // 9232 x 768 (reused for h2)
    unsigned short* mid   = (unsigned short*)(ws + 14164992);  // 9232 x 3072 aliases qkv+h (both dead)
    unsigned short* h2    = attno;                              // attno dead after o-proj

    // 1. weights -> bf16 transposed
    convert_w<<<4096, 256, 0, stream>>>(wq, wk, wv, wo, w1, w2, bq, bk, bv,
                                        wqkvT, woT, w1T, w2T, bqkv);
    // 2. LN1
    ln_bf16<<<MROWS, 256, 0, stream>>>(x, ln1_g, ln1_b, hbuf);
    // 3. QKV projection: qkv = h @ Wqkv + bqkv
    gemm128<0><<<dim3(2304 / 128, (MROWS + 127) / 128), 512, 0, stream>>>(
        hbuf, wqkvT, bqkv, qkv, nullptr, MROWS, 2304, 768);
    // 4. attention
    attn_kernel<<<dim3(19, BATCH * HEADS), 256, 0, stream>>>(qkv, attno);
    // 5. o-proj + residual: out = x + attno @ wo + bo
    gemm128<1><<<dim3(768 / 128, (MROWS + 127) / 128), 512, 0, stream>>>(
        attno, woT, bo, out, x, MROWS, 768, 768);
    // 6. LN2 (reads d_out) -> h2
    ln_bf16<<<MROWS, 256, 0, stream>>>(out, ln2_g, ln2_b, h2);
    // 7. MLP1 + gelu: mid = gelu(h2 @ w1 + b1)
    gemm128<2><<<dim3(3072 / 128, (MROWS + 127) / 128), 512, 0, stream>>>(
        h2, w1T, b1, mid, nullptr, MROWS, 3072, 768);
    // 8. MLP2 + residual in-place: out += mid @ w2 + b2
    gemm128<1><<<dim3(768 / 128, (MROWS + 127) / 128), 512, 0, stream>>>(
        mid, w2T, b2, out, out, MROWS, 768, 3072);
}

// Round 18
// 319.565 us; speedup vs baseline: 1.5373x; 1.0898x over previous
//
#include <hip/hip_runtime.h>
#include <hip/hip_bf16.h>

#define BATCH 16
#define SEQ   577
#define CDIM  768
#define HEADS 12
#define DHEAD 64
#define FFDIM 3072
#define MROWS (BATCH*SEQ)   // 9232

typedef __bf16 bf16x8 __attribute__((ext_vector_type(8)));
typedef float  f32x4  __attribute__((ext_vector_type(4)));
typedef unsigned short u16x8 __attribute__((ext_vector_type(8)));

__device__ __forceinline__ unsigned short f2bf(float f) {
    unsigned u = __builtin_bit_cast(unsigned, f);
    unsigned r = (u + 0x7FFFu + ((u >> 16) & 1u)) >> 16;
    return (unsigned short)r;
}
__device__ __forceinline__ float bf2f(unsigned short s) {
    return __builtin_bit_cast(float, (unsigned)s << 16);
}
__device__ __forceinline__ float gelu_f(float v) {
    return 0.5f * v * (1.f + erff(v * 0.7071067811865475f));
}
__device__ __forceinline__ void gll16(const void* g, void* l) {
    __builtin_amdgcn_global_load_lds(
        (const __attribute__((address_space(1))) unsigned int*)g,
        (__attribute__((address_space(3))) unsigned int*)l, 16, 0, 0);
}
#define MFMA16(a, b, c) __builtin_amdgcn_mfma_f32_16x16x32_bf16((a), (b), (c), 0, 0, 0)

// ---------------- weight conversion v2: LDS-tiled transpose, coalesced --------
// out[n][k] = bf16(in[k][n]). 32x32 tiles; float4 coalesced reads,
// ushort4 coalesced writes; LDS [32][33] (2-way max aliasing = free).
// Regions: [0,576) wq, [576,1152) wk, [1152,1728) wv, [1728,2304) wo,
// [2304,4608) w1, [4608,6912) w2, 6912: bqkv concat.
__global__ __launch_bounds__(256) void convert_wt(
    const float* __restrict__ wq, const float* __restrict__ wk, const float* __restrict__ wv,
    const float* __restrict__ wo, const float* __restrict__ w1, const float* __restrict__ w2,
    const float* __restrict__ bq, const float* __restrict__ bk, const float* __restrict__ bv,
    unsigned short* __restrict__ wqkvT, unsigned short* __restrict__ woT,
    unsigned short* __restrict__ w1T, unsigned short* __restrict__ w2T,
    float* __restrict__ bqkv)
{
    __shared__ float tile[32][33];
    int bidx = blockIdx.x;
    int t = threadIdx.x;
    if (bidx >= 6912) {
        for (int i = t; i < 2304; i += 256) {
            float v = (i < 768) ? bq[i] : (i < 1536) ? bk[i - 768] : bv[i - 1536];
            bqkv[i] = v;
        }
        return;
    }
    const float* src; unsigned short* dst; int K, N, tIdx;
    if (bidx < 576)       { src = wq; dst = wqkvT;              K = 768;  N = 768;  tIdx = bidx; }
    else if (bidx < 1152) { src = wk; dst = wqkvT + 768 * 768;  K = 768;  N = 768;  tIdx = bidx - 576; }
    else if (bidx < 1728) { src = wv; dst = wqkvT + 1536 * 768; K = 768;  N = 768;  tIdx = bidx - 1152; }
    else if (bidx < 2304) { src = wo; dst = woT;                K = 768;  N = 768;  tIdx = bidx - 1728; }
    else if (bidx < 4608) { src = w1; dst = w1T;                K = 768;  N = 3072; tIdx = bidx - 2304; }
    else                  { src = w2; dst = w2T;                K = 3072; N = 768;  tIdx = bidx - 4608; }
    int tilesN = N >> 5;
    int tk = tIdx / tilesN, tn = tIdx % tilesN;
    int k0 = tk * 32, n0 = tn * 32;
    {
        int r = t >> 3, c4 = (t & 7) * 4;
        float4 v = *(const float4*)(src + (size_t)(k0 + r) * N + n0 + c4);
        tile[r][c4 + 0] = v.x; tile[r][c4 + 1] = v.y;
        tile[r][c4 + 2] = v.z; tile[r][c4 + 3] = v.w;
    }
    __syncthreads();
    {
        int c = t >> 3, k4 = (t & 7) * 4;
        ushort4 ov;
        ov.x = f2bf(tile[k4 + 0][c]);
        ov.y = f2bf(tile[k4 + 1][c]);
        ov.z = f2bf(tile[k4 + 2][c]);
        ov.w = f2bf(tile[k4 + 3][c]);
        *(ushort4*)(dst + (size_t)(n0 + c) * K + k0 + k4) = ov;
    }
}

// ---------------- LayerNorm (row of 768) -> bf16 ------------------------------
__global__ __launch_bounds__(256) void ln_bf16(
    const float* __restrict__ x, const float* __restrict__ g, const float* __restrict__ b,
    unsigned short* __restrict__ out)
{
    int row = blockIdx.x;
    int t = threadIdx.x;
    const float* xr = x + (size_t)row * CDIM;
    float v0 = xr[t], v1 = xr[t + 256], v2 = xr[t + 512];
    float s = v0 + v1 + v2;
    float q = v0 * v0 + v1 * v1 + v2 * v2;
    __shared__ float red[8];
    for (int o = 32; o > 0; o >>= 1) { s += __shfl_down(s, o); q += __shfl_down(q, o); }
    int wid = t >> 6;
    if ((t & 63) == 0) { red[wid] = s; red[4 + wid] = q; }
    __syncthreads();
    if (t == 0) {
        float S = red[0] + red[1] + red[2] + red[3];
        float Q = red[4] + red[5] + red[6] + red[7];
        float mu = S * (1.f / CDIM);
        float var = Q * (1.f / CDIM) - mu * mu;
        red[0] = mu; red[1] = rsqrtf(var + 1e-5f);
    }
    __syncthreads();
    float mu = red[0], rs = red[1];
    unsigned short* orow = out + (size_t)row * CDIM;
    orow[t]       = f2bf((v0 - mu) * rs * g[t]       + b[t]);
    orow[t + 256] = f2bf((v1 - mu) * rs * g[t + 256] + b[t + 256]);
    orow[t + 512] = f2bf((v2 - mu) * rs * g[t + 512] + b[t + 512]);
}

// ---------------- GEMM 128x128, BK=64, dbuf, 8 waves, XOR-swizzled LDS --------
// (round-14/15 structure — best measured)
template<int EPI>
__global__ __launch_bounds__(512, 4) void gemm128(
    const unsigned short* __restrict__ A, const unsigned short* __restrict__ Bt,
    const float* __restrict__ bias, void* __restrict__ Cout,
    const float* __restrict__ resid, int M, int Nn, int K)
{
    __shared__ __align__(16) unsigned short As[2][128 * 64];
    __shared__ __align__(16) unsigned short Bs[2][128 * 64];

    int t = threadIdx.x;
    int gx = gridDim.x;
    int nwg = gx * gridDim.y;
    int bid = blockIdx.y * gx + blockIdx.x;
    int qc = nwg >> 3, rc = nwg & 7;
    int xcd = bid & 7, loc = bid >> 3;
    int swz = (xcd < rc ? xcd * (qc + 1) : rc * (qc + 1) + (xcd - rc) * qc) + loc;
    int nbase = (swz % gx) * 128;
    int mbase = (swz / gx) * 128;

    int lane = t & 63, w = t >> 6;          // w = 0..7
    int wm = w >> 2, wn = w & 3;            // 2(M) x 4(N) wave grid
    int lr = lane & 15, lk = lane >> 4;

    int srow = lane >> 3;                      // 0..7 row within 8-row sweep
    int scol = ((lane & 7) * 8) ^ (srow << 3); // pre-swizzled col (elems)

    int arow0 = min(mbase + w * 16 + srow,     M - 1);
    int arow1 = min(mbase + w * 16 + 8 + srow, M - 1);
    int brow0 = nbase + w * 16 + srow;
    int brow1 = nbase + w * 16 + 8 + srow;
    const unsigned short* ap0 = A  + (size_t)arow0 * K + scol;
    const unsigned short* ap1 = A  + (size_t)arow1 * K + scol;
    const unsigned short* bp0 = Bt + (size_t)brow0 * K + scol;
    const unsigned short* bp1 = Bt + (size_t)brow1 * K + scol;
    char* lA[2] = { (char*)&As[0][0] + w * 2048, (char*)&As[1][0] + w * 2048 };
    char* lB[2] = { (char*)&Bs[0][0] + w * 2048, (char*)&Bs[1][0] + w * 2048 };

    f32x4 acc[4][2] = {};

    gll16(ap0, lA[0]);
    gll16(ap1, lA[0] + 1024);
    gll16(bp0, lB[0]);
    gll16(bp1, lB[0] + 1024);

    for (int kt = 0; kt < K; kt += 64) {
        int buf = (kt >> 6) & 1;
        __syncthreads();
        if (kt + 64 < K) {
            gll16(ap0 + kt + 64, lA[buf ^ 1]);
            gll16(ap1 + kt + 64, lA[buf ^ 1] + 1024);
            gll16(bp0 + kt + 64, lB[buf ^ 1]);
            gll16(bp1 + kt + 64, lB[buf ^ 1] + 1024);
        }
        bf16x8 af[4][2], bfv[2][2];
#pragma unroll
        for (int mi = 0; mi < 4; mi++) {
            int row = wm * 64 + mi * 16 + lr;
#pragma unroll
            for (int ks = 0; ks < 2; ks++)
                af[mi][ks] = *(const bf16x8*)((char*)&As[buf][0] + row * 128 +
                                (((ks * 64 + lk * 16)) ^ ((lr & 7) << 4)));
        }
#pragma unroll
        for (int ni = 0; ni < 2; ni++) {
            int row = wn * 32 + ni * 16 + lr;
#pragma unroll
            for (int ks = 0; ks < 2; ks++)
                bfv[ni][ks] = *(const bf16x8*)((char*)&Bs[buf][0] + row * 128 +
                                (((ks * 64 + lk * 16)) ^ ((lr & 7) << 4)));
        }
#pragma unroll
        for (int ks = 0; ks < 2; ks++)
#pragma unroll
            for (int mi = 0; mi < 4; mi++)
#pragma unroll
                for (int ni = 0; ni < 2; ni++)
                    acc[mi][ni] = MFMA16(af[mi][ks], bfv[ni][ks], acc[mi][ni]);
    }

#pragma unroll
    for (int mi = 0; mi < 4; mi++) {
#pragma unroll
        for (int ni = 0; ni < 2; ni++) {
            int col = nbase + wn * 32 + ni * 16 + lr;
            float bcol = bias[col];
#pragma unroll
            for (int i = 0; i < 4; i++) {
                int row = mbase + wm * 64 + mi * 16 + lk * 4 + i;
                if (row >= M) continue;
                float v = acc[mi][ni][i] + bcol;
                if (EPI == 0) {
                    ((unsigned short*)Cout)[(size_t)row * Nn + col] = f2bf(v);
                } else if (EPI == 1) {
                    ((float*)Cout)[(size_t)row * Nn + col] = resid[(size_t)row * Nn + col] + v;
                } else {
                    ((unsigned short*)Cout)[(size_t)row * Nn + col] = f2bf(gelu_f(v));
                }
            }
        }
    }
}

// ---------------- fused attention v6: XCD swizzle + fused exp (no max-pass) ---
__global__ __launch_bounds__(256) void attn_kernel(
    const unsigned short* __restrict__ qkv, unsigned short* __restrict__ attno)
{
    int bid = blockIdx.y * 19 + blockIdx.x;
    int swzb = (bid & 7) * 456 + (bid >> 3);   // nwg=3648, rc=0
    int qt = swzb % 19;
    int bh = swzb / 19;
    int b = bh / HEADS, h = bh % HEADS;
    int t = threadIdx.x;
    int lane = t & 63, w = t >> 6;
    int lr = lane & 15, lk = lane >> 4, k0 = lk * 8;

    const size_t baseRow = (size_t)b * SEQ;
    const unsigned short* Qp = qkv + baseRow * 2304 + h * 64;
    const unsigned short* Kp = Qp + 768;
    const unsigned short* Vp = Qp + 1536;

    __shared__ __align__(16) unsigned short sSP[32][648];  // P (bf16), 81 slots/row
    __shared__ __align__(16) unsigned short sVt[64 * 64];  // V^T chunk, XOR-swizzled
    __shared__ float sRedS[4][32];

    // ---- Q fragments in registers; V chunk-0 load issued early (T14) ----------
    bf16x8 afr[2][2];
#pragma unroll
    for (int mi = 0; mi < 2; mi++) {
        int qr = qt * 32 + mi * 16 + lr; if (qr > SEQ - 1) qr = SEQ - 1;
#pragma unroll
        for (int ks = 0; ks < 2; ks++)
            afr[mi][ks] = *(const bf16x8*)(Qp + (size_t)qr * 2304 + ks * 32 + k0);
    }
    int jp = t >> 3;               // 0..31 -> j pair within chunk
    int dg = (t & 7) * 8;          // d group
    u16x8 vA, vB;
    vA = *(const u16x8*)(Vp + (size_t)min(jp * 2,     SEQ - 1) * 2304 + dg);
    vB = *(const u16x8*)(Vp + (size_t)min(jp * 2 + 1, SEQ - 1) * 2304 + dg);

    // ---- QK^T fused with exp + P-write + row-sum: wave w owns j-tiles w+4it ---
    float sm[2][4] = {};
#pragma unroll
    for (int it = 0; it < 10; it++) {
        int jt = w + it * 4;
        int col = jt * 16 + lr;
        int j = min(col, SEQ - 1);
        f32x4 a0 = {}, a1 = {};
#pragma unroll
        for (int ks = 0; ks < 2; ks++) {
            bf16x8 bfr = *(const bf16x8*)(Kp + (size_t)j * 2304 + ks * 32 + k0);
            a0 = MFMA16(afr[0][ks], bfr, a0);
            a1 = MFMA16(afr[1][ks], bfr, a1);
        }
        bool valid = col < SEQ;
#pragma unroll
        for (int i = 0; i < 4; i++) {
            float p0 = valid ? __expf(0.125f * a0[i]) : 0.f;
            float p1 = valid ? __expf(0.125f * a1[i]) : 0.f;
            sm[0][i] += p0;
            sm[1][i] += p1;
            sSP[lk * 4 + i][col]      = f2bf(p0);
            sSP[16 + lk * 4 + i][col] = f2bf(p1);
        }
    }
    // reduce row-sums over the 16 lr lanes, publish per-wave
#pragma unroll
    for (int mi = 0; mi < 2; mi++) {
#pragma unroll
        for (int i = 0; i < 4; i++) {
            float v = sm[mi][i];
            v += __shfl_xor(v, 1);
            v += __shfl_xor(v, 2);
            v += __shfl_xor(v, 4);
            v += __shfl_xor(v, 8);
            sm[mi][i] = v;
        }
    }
    if (lr == 0)
#pragma unroll
        for (int mi = 0; mi < 2; mi++)
#pragma unroll
            for (int i = 0; i < 4; i++)
                sRedS[w][mi * 16 + lk * 4 + i] = sm[mi][i];
    __syncthreads();

    // ---- PV: 10 chunks of 64 j; T14 pipeline: write regs->LDS, issue next -----
    f32x4 oacc[2] = {};
    int d = w * 16 + lr;
    int fx = ((d & 7) ^ (d >> 3)) << 4;
    for (int jc = 0; jc < 10; jc++) {
        __syncthreads();               // previous chunk's sVt readers done
#pragma unroll
        for (int e = 0; e < 8; e++) {
            unsigned val = (unsigned)vA[e] | ((unsigned)vB[e] << 16);
            int r = dg + e;
            int off = (r * 128 + jp * 4) ^ ((((r & 7) ^ (r >> 3)) & 7) << 4);
            *(unsigned*)((char*)sVt + off) = val;
        }
        if (jc < 9) {
            int j0 = (jc + 1) * 64 + jp * 2;
            vA = *(const u16x8*)(Vp + (size_t)min(j0,     SEQ - 1) * 2304 + dg);
            vB = *(const u16x8*)(Vp + (size_t)min(j0 + 1, SEQ - 1) * 2304 + dg);
        }
        __syncthreads();               // sVt(jc) ready
#pragma unroll
        for (int ks = 0; ks < 2; ks++) {
            bf16x8 vb = *(const bf16x8*)((char*)sVt + ((d * 128 + ks * 64 + lk * 16) ^ fx));
#pragma unroll
            for (int mi = 0; mi < 2; mi++) {
                bf16x8 pa = *(const bf16x8*)&sSP[mi * 16 + lr][jc * 64 + ks * 32 + k0];
                oacc[mi] = MFMA16(pa, vb, oacc[mi]);
            }
        }
    }

#pragma unroll
    for (int mi = 0; mi < 2; mi++) {
#pragma unroll
        for (int i = 0; i < 4; i++) {
            int ri = mi * 16 + lk * 4 + i;
            int qr = qt * 32 + ri;
            if (qr < SEQ) {
                float rs = sRedS[0][ri] + sRedS[1][ri] + sRedS[2][ri] + sRedS[3][ri];
                float ov = oacc[mi][i] / rs;
                attno[(baseRow + qr) * CDIM + h * 64 + w * 16 + lr] = f2bf(ov);
            }
        }
    }
}

// ---------------- host launch --------------------------------------------------
extern "C" void kernel_launch(void* const* d_in, const int* in_sizes, int n_in,
                              void* d_out, int out_size, void* d_ws, size_t ws_size,
                              hipStream_t stream) {
    const float* x     = (const float*)d_in[0];
    const float* ln1_g = (const float*)d_in[2];
    const float* ln1_b = (const float*)d_in[3];
    const float* wq    = (const float*)d_in[4];
    const float* bq    = (const float*)d_in[5];
    const float* wk    = (const float*)d_in[6];
    const float* bk    = (const float*)d_in[7];
    const float* wv    = (const float*)d_in[8];
    const float* bv    = (const float*)d_in[9];
    const float* wo    = (const float*)d_in[10];
    const float* bo    = (const float*)d_in[11];
    const float* ln2_g = (const float*)d_in[12];
    const float* ln2_b = (const float*)d_in[13];
    const float* w1    = (const float*)d_in[14];
    const float* b1    = (const float*)d_in[15];
    const float* w2    = (const float*)d_in[16];
    const float* b2    = (const float*)d_in[17];
    float* out = (float*)d_out;

    char* ws = (char*)d_ws;
    unsigned short* wqkvT = (unsigned short*)(ws + 0);
    unsigned short* woT   = (unsigned short*)(ws + 3538944);
    unsigned short* w1T   = (unsigned short*)(ws + 4718592);
    unsigned short* w2T   = (unsigned short*)(ws + 9437184);
    float*          bqkv  = (float*)         (ws + 14155776);
    unsigned short* qkv   = (unsigned short*)(ws + 14164992);  // 9232 x 2304
    unsigned short* hbuf  = (unsigned short*)(ws + 56706048);  // 9232 x 768
    unsigned short* attno = (unsigned short*)(ws + 70886400);  // 9232 x 768 (reused for h2)
    unsigned short* mid   = (unsigned short*)(ws + 14164992);  // 9232 x 3072 aliases qkv+h (both dead)
    unsigned short* h2    = attno;                              // attno dead after o-proj

    // 1. weights -> bf16 transposed (tiled, coalesced)
    convert_wt<<<6913, 256, 0, stream>>>(wq, wk, wv, wo, w1, w2, bq, bk, bv,
                                         wqkvT, woT, w1T, w2T, bqkv);
    // 2. LN1
    ln_bf16<<<MROWS, 256, 0, stream>>>(x, ln1_g, ln1_b, hbuf);
    // 3. QKV projection: qkv = h @ Wqkv + bqkv
    gemm128<0><<<dim3(2304 / 128, (MROWS + 127) / 128), 512, 0, stream>>>(
        hbuf, wqkvT, bqkv, qkv, nullptr, MROWS, 2304, 768);
    // 4. attention
    attn_kernel<<<dim3(19, BATCH * HEADS), 256, 0, stream>>>(qkv, attno);
    // 5. o-proj + residual: out = x + attno @ wo + bo
    gemm128<1><<<dim3(768 / 128, (MROWS + 127) / 128), 512, 0, stream>>>(
        attno, woT, bo, out, x, MROWS, 768, 768);
    // 6. LN2 (reads d_out) -> h2
    ln_bf16<<<MROWS, 256, 0, stream>>>(out, ln2_g, ln2_b, h2);
    // 7. MLP1 + gelu: mid = gelu(h2 @ w1 + b1)
    gemm128<2><<<dim3(3072 / 128, (MROWS + 127) / 128), 512, 0, stream>>>(
        h2, w1T, b1, mid, nullptr, MROWS, 3072, 768);
    // 8. MLP2 + residual in-place: out += mid @ w2 + b2
    gemm128<1><<<dim3(768 / 128, (MROWS + 127) / 128), 512, 0, stream>>>(
        mid, w2T, b2, out, out, MROWS, 768, 3072);
}

// Round 19
// 313.599 us; speedup vs baseline: 1.5666x; 1.0190x over previous
//
#include <hip/hip_runtime.h>
#include <hip/hip_bf16.h>

#define BATCH 16
#define SEQ   577
#define CDIM  768
#define HEADS 12
#define DHEAD 64
#define FFDIM 3072
#define MROWS (BATCH*SEQ)   // 9232

typedef __bf16 bf16x8 __attribute__((ext_vector_type(8)));
typedef float  f32x4  __attribute__((ext_vector_type(4)));
typedef unsigned short u16x8 __attribute__((ext_vector_type(8)));

__device__ __forceinline__ unsigned short f2bf(float f) {
    unsigned u = __builtin_bit_cast(unsigned, f);
    unsigned r = (u + 0x7FFFu + ((u >> 16) & 1u)) >> 16;
    return (unsigned short)r;
}
__device__ __forceinline__ float bf2f(unsigned short s) {
    return __builtin_bit_cast(float, (unsigned)s << 16);
}
__device__ __forceinline__ float gelu_f(float v) {
    return 0.5f * v * (1.f + erff(v * 0.7071067811865475f));
}
__device__ __forceinline__ void gll16(const void* g, void* l) {
    __builtin_amdgcn_global_load_lds(
        (const __attribute__((address_space(1))) unsigned int*)g,
        (__attribute__((address_space(3))) unsigned int*)l, 16, 0, 0);
}
#define MFMA16(a, b, c) __builtin_amdgcn_mfma_f32_16x16x32_bf16((a), (b), (c), 0, 0, 0)

// ---------------- weight conversion v2: LDS-tiled transpose, coalesced --------
__global__ __launch_bounds__(256) void convert_wt(
    const float* __restrict__ wq, const float* __restrict__ wk, const float* __restrict__ wv,
    const float* __restrict__ wo, const float* __restrict__ w1, const float* __restrict__ w2,
    const float* __restrict__ bq, const float* __restrict__ bk, const float* __restrict__ bv,
    unsigned short* __restrict__ wqkvT, unsigned short* __restrict__ woT,
    unsigned short* __restrict__ w1T, unsigned short* __restrict__ w2T,
    float* __restrict__ bqkv)
{
    __shared__ float tile[32][33];
    int bidx = blockIdx.x;
    int t = threadIdx.x;
    if (bidx >= 6912) {
        for (int i = t; i < 2304; i += 256) {
            float v = (i < 768) ? bq[i] : (i < 1536) ? bk[i - 768] : bv[i - 1536];
            bqkv[i] = v;
        }
        return;
    }
    const float* src; unsigned short* dst; int K, N, tIdx;
    if (bidx < 576)       { src = wq; dst = wqkvT;              K = 768;  N = 768;  tIdx = bidx; }
    else if (bidx < 1152) { src = wk; dst = wqkvT + 768 * 768;  K = 768;  N = 768;  tIdx = bidx - 576; }
    else if (bidx < 1728) { src = wv; dst = wqkvT + 1536 * 768; K = 768;  N = 768;  tIdx = bidx - 1152; }
    else if (bidx < 2304) { src = wo; dst = woT;                K = 768;  N = 768;  tIdx = bidx - 1728; }
    else if (bidx < 4608) { src = w1; dst = w1T;                K = 768;  N = 3072; tIdx = bidx - 2304; }
    else                  { src = w2; dst = w2T;                K = 3072; N = 768;  tIdx = bidx - 4608; }
    int tilesN = N >> 5;
    int tk = tIdx / tilesN, tn = tIdx % tilesN;
    int k0 = tk * 32, n0 = tn * 32;
    {
        int r = t >> 3, c4 = (t & 7) * 4;
        float4 v = *(const float4*)(src + (size_t)(k0 + r) * N + n0 + c4);
        tile[r][c4 + 0] = v.x; tile[r][c4 + 1] = v.y;
        tile[r][c4 + 2] = v.z; tile[r][c4 + 3] = v.w;
    }
    __syncthreads();
    {
        int c = t >> 3, k4 = (t & 7) * 4;
        ushort4 ov;
        ov.x = f2bf(tile[k4 + 0][c]);
        ov.y = f2bf(tile[k4 + 1][c]);
        ov.z = f2bf(tile[k4 + 2][c]);
        ov.w = f2bf(tile[k4 + 3][c]);
        *(ushort4*)(dst + (size_t)(n0 + c) * K + k0 + k4) = ov;
    }
}

// ---------------- LayerNorm (row of 768) -> bf16 ------------------------------
__global__ __launch_bounds__(256) void ln_bf16(
    const float* __restrict__ x, const float* __restrict__ g, const float* __restrict__ b,
    unsigned short* __restrict__ out)
{
    int row = blockIdx.x;
    int t = threadIdx.x;
    const float* xr = x + (size_t)row * CDIM;
    float v0 = xr[t], v1 = xr[t + 256], v2 = xr[t + 512];
    float s = v0 + v1 + v2;
    float q = v0 * v0 + v1 * v1 + v2 * v2;
    __shared__ float red[8];
    for (int o = 32; o > 0; o >>= 1) { s += __shfl_down(s, o); q += __shfl_down(q, o); }
    int wid = t >> 6;
    if ((t & 63) == 0) { red[wid] = s; red[4 + wid] = q; }
    __syncthreads();
    if (t == 0) {
        float S = red[0] + red[1] + red[2] + red[3];
        float Q = red[4] + red[5] + red[6] + red[7];
        float mu = S * (1.f / CDIM);
        float var = Q * (1.f / CDIM) - mu * mu;
        red[0] = mu; red[1] = rsqrtf(var + 1e-5f);
    }
    __syncthreads();
    float mu = red[0], rs = red[1];
    unsigned short* orow = out + (size_t)row * CDIM;
    orow[t]       = f2bf((v0 - mu) * rs * g[t]       + b[t]);
    orow[t + 256] = f2bf((v1 - mu) * rs * g[t + 256] + b[t + 256]);
    orow[t + 512] = f2bf((v2 - mu) * rs * g[t + 512] + b[t + 512]);
}

// ---------------- GEMM 128x128, BK=64, dbuf, 8 waves, XOR-swizzled LDS --------
// r14/15 inner structure + 2D XCD partition: xcd=(mquad,nhalf) so each XCD's
// B working set (<=2.3 MB) stays L2-resident; A streamed (read by 2 XCDs).
// Grid y = 76 M-tiles (padded); pad blocks exit immediately. gridDim.x even.
template<int EPI>
__global__ __launch_bounds__(512, 4) void gemm128(
    const unsigned short* __restrict__ A, const unsigned short* __restrict__ Bt,
    const float* __restrict__ bias, void* __restrict__ Cout,
    const float* __restrict__ resid, int M, int Nn, int K)
{
    __shared__ __align__(16) unsigned short As[2][128 * 64];
    __shared__ __align__(16) unsigned short Bs[2][128 * 64];

    int t = threadIdx.x;
    // 2D XCD partition: nhalf = xcd&1 (N/2), mquad = xcd>>1 (19 M-tiles each).
    int gx = gridDim.x;                  // N tiles (even)
    int bid = blockIdx.y * gx + blockIdx.x;
    int xcd = bid & 7;
    int loc = bid >> 3;                  // [0, gx*76/8) = [0, gx/2*19)
    int nhw = gx >> 1;
    int nloc = loc % nhw, mloc = loc / nhw;      // mloc in [0,19)
    int nbase = ((xcd & 1) * nhw + nloc) * 128;
    int mbase = ((xcd >> 1) * 19 + mloc) * 128;
    if (mbase >= M) return;              // padded M-tiles (73..75)

    int lane = t & 63, w = t >> 6;          // w = 0..7
    int wm = w >> 2, wn = w & 3;            // 2(M) x 4(N) wave grid
    int lr = lane & 15, lk = lane >> 4;

    int srow = lane >> 3;                      // 0..7 row within 8-row sweep
    int scol = ((lane & 7) * 8) ^ (srow << 3); // pre-swizzled col (elems)

    int arow0 = min(mbase + w * 16 + srow,     M - 1);
    int arow1 = min(mbase + w * 16 + 8 + srow, M - 1);
    int brow0 = nbase + w * 16 + srow;
    int brow1 = nbase + w * 16 + 8 + srow;
    const unsigned short* ap0 = A  + (size_t)arow0 * K + scol;
    const unsigned short* ap1 = A  + (size_t)arow1 * K + scol;
    const unsigned short* bp0 = Bt + (size_t)brow0 * K + scol;
    const unsigned short* bp1 = Bt + (size_t)brow1 * K + scol;
    char* lA[2] = { (char*)&As[0][0] + w * 2048, (char*)&As[1][0] + w * 2048 };
    char* lB[2] = { (char*)&Bs[0][0] + w * 2048, (char*)&Bs[1][0] + w * 2048 };

    f32x4 acc[4][2] = {};

    gll16(ap0, lA[0]);
    gll16(ap1, lA[0] + 1024);
    gll16(bp0, lB[0]);
    gll16(bp1, lB[0] + 1024);

    for (int kt = 0; kt < K; kt += 64) {
        int buf = (kt >> 6) & 1;
        __syncthreads();
        if (kt + 64 < K) {
            gll16(ap0 + kt + 64, lA[buf ^ 1]);
            gll16(ap1 + kt + 64, lA[buf ^ 1] + 1024);
            gll16(bp0 + kt + 64, lB[buf ^ 1]);
            gll16(bp1 + kt + 64, lB[buf ^ 1] + 1024);
        }
        bf16x8 af[4][2], bfv[2][2];
#pragma unroll
        for (int mi = 0; mi < 4; mi++) {
            int row = wm * 64 + mi * 16 + lr;
#pragma unroll
            for (int ks = 0; ks < 2; ks++)
                af[mi][ks] = *(const bf16x8*)((char*)&As[buf][0] + row * 128 +
                                (((ks * 64 + lk * 16)) ^ ((lr & 7) << 4)));
        }
#pragma unroll
        for (int ni = 0; ni < 2; ni++) {
            int row = wn * 32 + ni * 16 + lr;
#pragma unroll
            for (int ks = 0; ks < 2; ks++)
                bfv[ni][ks] = *(const bf16x8*)((char*)&Bs[buf][0] + row * 128 +
                                (((ks * 64 + lk * 16)) ^ ((lr & 7) << 4)));
        }
#pragma unroll
        for (int ks = 0; ks < 2; ks++)
#pragma unroll
            for (int mi = 0; mi < 4; mi++)
#pragma unroll
                for (int ni = 0; ni < 2; ni++)
                    acc[mi][ni] = MFMA16(af[mi][ks], bfv[ni][ks], acc[mi][ni]);
    }

#pragma unroll
    for (int mi = 0; mi < 4; mi++) {
#pragma unroll
        for (int ni = 0; ni < 2; ni++) {
            int col = nbase + wn * 32 + ni * 16 + lr;
            float bcol = bias[col];
#pragma unroll
            for (int i = 0; i < 4; i++) {
                int row = mbase + wm * 64 + mi * 16 + lk * 4 + i;
                if (row >= M) continue;
                float v = acc[mi][ni][i] + bcol;
                if (EPI == 0) {
                    ((unsigned short*)Cout)[(size_t)row * Nn + col] = f2bf(v);
                } else if (EPI == 1) {
                    ((float*)Cout)[(size_t)row * Nn + col] = resid[(size_t)row * Nn + col] + v;
                } else {
                    ((unsigned short*)Cout)[(size_t)row * Nn + col] = f2bf(gelu_f(v));
                }
            }
        }
    }
}

// ---------------- fused attention v6: XCD swizzle + fused exp (no max-pass) ---
__global__ __launch_bounds__(256) void attn_kernel(
    const unsigned short* __restrict__ qkv, unsigned short* __restrict__ attno)
{
    int bid = blockIdx.y * 19 + blockIdx.x;
    int swzb = (bid & 7) * 456 + (bid >> 3);   // nwg=3648, rc=0
    int qt = swzb % 19;
    int bh = swzb / 19;
    int b = bh / HEADS, h = bh % HEADS;
    int t = threadIdx.x;
    int lane = t & 63, w = t >> 6;
    int lr = lane & 15, lk = lane >> 4, k0 = lk * 8;

    const size_t baseRow = (size_t)b * SEQ;
    const unsigned short* Qp = qkv + baseRow * 2304 + h * 64;
    const unsigned short* Kp = Qp + 768;
    const unsigned short* Vp = Qp + 1536;

    __shared__ __align__(16) unsigned short sSP[32][648];  // P (bf16), 81 slots/row
    __shared__ __align__(16) unsigned short sVt[64 * 64];  // V^T chunk, XOR-swizzled
    __shared__ float sRedS[4][32];

    // ---- Q fragments in registers; V chunk-0 load issued early (T14) ----------
    bf16x8 afr[2][2];
#pragma unroll
    for (int mi = 0; mi < 2; mi++) {
        int qr = qt * 32 + mi * 16 + lr; if (qr > SEQ - 1) qr = SEQ - 1;
#pragma unroll
        for (int ks = 0; ks < 2; ks++)
            afr[mi][ks] = *(const bf16x8*)(Qp + (size_t)qr * 2304 + ks * 32 + k0);
    }
    int jp = t >> 3;               // 0..31 -> j pair within chunk
    int dg = (t & 7) * 8;          // d group
    u16x8 vA, vB;
    vA = *(const u16x8*)(Vp + (size_t)min(jp * 2,     SEQ - 1) * 2304 + dg);
    vB = *(const u16x8*)(Vp + (size_t)min(jp * 2 + 1, SEQ - 1) * 2304 + dg);

    // ---- QK^T fused with exp + P-write + row-sum: wave w owns j-tiles w+4it ---
    float sm[2][4] = {};
#pragma unroll
    for (int it = 0; it < 10; it++) {
        int jt = w + it * 4;
        int col = jt * 16 + lr;
        int j = min(col, SEQ - 1);
        f32x4 a0 = {}, a1 = {};
#pragma unroll
        for (int ks = 0; ks < 2; ks++) {
            bf16x8 bfr = *(const bf16x8*)(Kp + (size_t)j * 2304 + ks * 32 + k0);
            a0 = MFMA16(afr[0][ks], bfr, a0);
            a1 = MFMA16(afr[1][ks], bfr, a1);
        }
        bool valid = col < SEQ;
#pragma unroll
        for (int i = 0; i < 4; i++) {
            float p0 = valid ? __expf(0.125f * a0[i]) : 0.f;
            float p1 = valid ? __expf(0.125f * a1[i]) : 0.f;
            sm[0][i] += p0;
            sm[1][i] += p1;
            sSP[lk * 4 + i][col]      = f2bf(p0);
            sSP[16 + lk * 4 + i][col] = f2bf(p1);
        }
    }
    // reduce row-sums over the 16 lr lanes, publish per-wave
#pragma unroll
    for (int mi = 0; mi < 2; mi++) {
#pragma unroll
        for (int i = 0; i < 4; i++) {
            float v = sm[mi][i];
            v += __shfl_xor(v, 1);
            v += __shfl_xor(v, 2);
            v += __shfl_xor(v, 4);
            v += __shfl_xor(v, 8);
            sm[mi][i] = v;
        }
    }
    if (lr == 0)
#pragma unroll
        for (int mi = 0; mi < 2; mi++)
#pragma unroll
            for (int i = 0; i < 4; i++)
                sRedS[w][mi * 16 + lk * 4 + i] = sm[mi][i];
    __syncthreads();

    // ---- PV: 10 chunks of 64 j; T14 pipeline: write regs->LDS, issue next -----
    f32x4 oacc[2] = {};
    int d = w * 16 + lr;
    int fx = ((d & 7) ^ (d >> 3)) << 4;
    for (int jc = 0; jc < 10; jc++) {
        __syncthreads();               // previous chunk's sVt readers done
#pragma unroll
        for (int e = 0; e < 8; e++) {
            unsigned val = (unsigned)vA[e] | ((unsigned)vB[e] << 16);
            int r = dg + e;
            int off = (r * 128 + jp * 4) ^ ((((r & 7) ^ (r >> 3)) & 7) << 4);
            *(unsigned*)((char*)sVt + off) = val;
        }
        if (jc < 9) {
            int j0 = (jc + 1) * 64 + jp * 2;
            vA = *(const u16x8*)(Vp + (size_t)min(j0,     SEQ - 1) * 2304 + dg);
            vB = *(const u16x8*)(Vp + (size_t)min(j0 + 1, SEQ - 1) * 2304 + dg);
        }
        __syncthreads();               // sVt(jc) ready
#pragma unroll
        for (int ks = 0; ks < 2; ks++) {
            bf16x8 vb = *(const bf16x8*)((char*)sVt + ((d * 128 + ks * 64 + lk * 16) ^ fx));
#pragma unroll
            for (int mi = 0; mi < 2; mi++) {
                bf16x8 pa = *(const bf16x8*)&sSP[mi * 16 + lr][jc * 64 + ks * 32 + k0];
                oacc[mi] = MFMA16(pa, vb, oacc[mi]);
            }
        }
    }

#pragma unroll
    for (int mi = 0; mi < 2; mi++) {
#pragma unroll
        for (int i = 0; i < 4; i++) {
            int ri = mi * 16 + lk * 4 + i;
            int qr = qt * 32 + ri;
            if (qr < SEQ) {
                float rs = sRedS[0][ri] + sRedS[1][ri] + sRedS[2][ri] + sRedS[3][ri];
                float ov = oacc[mi][i] / rs;
                attno[(baseRow + qr) * CDIM + h * 64 + w * 16 + lr] = f2bf(ov);
            }
        }
    }
}

// ---------------- host launch --------------------------------------------------
extern "C" void kernel_launch(void* const* d_in, const int* in_sizes, int n_in,
                              void* d_out, int out_size, void* d_ws, size_t ws_size,
                              hipStream_t stream) {
    const float* x     = (const float*)d_in[0];
    const float* ln1_g = (const float*)d_in[2];
    const float* ln1_b = (const float*)d_in[3];
    const float* wq    = (const float*)d_in[4];
    const float* bq    = (const float*)d_in[5];
    const float* wk    = (const float*)d_in[6];
    const float* bk    = (const float*)d_in[7];
    const float* wv    = (const float*)d_in[8];
    const float* bv    = (const float*)d_in[9];
    const float* wo    = (const float*)d_in[10];
    const float* bo    = (const float*)d_in[11];
    const float* ln2_g = (const float*)d_in[12];
    const float* ln2_b = (const float*)d_in[13];
    const float* w1    = (const float*)d_in[14];
    const float* b1    = (const float*)d_in[15];
    const float* w2    = (const float*)d_in[16];
    const float* b2    = (const float*)d_in[17];
    float* out = (float*)d_out;

    char* ws = (char*)d_ws;
    unsigned short* wqkvT = (unsigned short*)(ws + 0);
    unsigned short* woT   = (unsigned short*)(ws + 3538944);
    unsigned short* w1T   = (unsigned short*)(ws + 4718592);
    unsigned short* w2T   = (unsigned short*)(ws + 9437184);
    float*          bqkv  = (float*)         (ws + 14155776);
    unsigned short* qkv   = (unsigned short*)(ws + 14164992);  // 9232 x 2304
    unsigned short* hbuf  = (unsigned short*)(ws + 56706048);  // 9232 x 768
    unsigned short* attno = (unsigned short*)(ws + 70886400);  // 9232 x 768 (reused for h2)
    unsigned short* mid   = (unsigned short*)(ws + 14164992);  // 9232 x 3072 aliases qkv+h (both dead)
    unsigned short* h2    = attno;                              // attno dead after o-proj

    // 1. weights -> bf16 transposed (tiled, coalesced)
    convert_wt<<<6913, 256, 0, stream>>>(wq, wk, wv, wo, w1, w2, bq, bk, bv,
                                         wqkvT, woT, w1T, w2T, bqkv);
    // 2. LN1
    ln_bf16<<<MROWS, 256, 0, stream>>>(x, ln1_g, ln1_b, hbuf);
    // 3. QKV projection: qkv = h @ Wqkv + bqkv  (grid y padded to 76 M-tiles)
    gemm128<0><<<dim3(2304 / 128, 76), 512, 0, stream>>>(
        hbuf, wqkvT, bqkv, qkv, nullptr, MROWS, 2304, 768);
    // 4. attention
    attn_kernel<<<dim3(19, BATCH * HEADS), 256, 0, stream>>>(qkv, attno);
    // 5. o-proj + residual: out = x + attno @ wo + bo
    gemm128<1><<<dim3(768 / 128, 76), 512, 0, stream>>>(
        attno, woT, bo, out, x, MROWS, 768, 768);
    // 6. LN2 (reads d_out) -> h2
    ln_bf16<<<MROWS, 256, 0, stream>>>(out, ln2_g, ln2_b, h2);
    // 7. MLP1 + gelu: mid = gelu(h2 @ w1 + b1)
    gemm128<2><<<dim3(3072 / 128, 76), 512, 0, stream>>>(
        h2, w1T, b1, mid, nullptr, MROWS, 3072, 768);
    // 8. MLP2 + residual in-place: out += mid @ w2 + b2
    gemm128<1><<<dim3(768 / 128, 76), 512, 0, stream>>>(
        mid, w2T, b2, out, out, MROWS, 768, 3072);
}